// Round 6
// baseline (303.506 us; speedup 1.0000x reference)
//
#include <hip/hip_runtime.h>

#define D 64
#define CHUNK 4096          // edges per partition block (391 blocks, 1024 thr -> 4 passes)
#define BKT_SHIFT 8         // 256 nodes per bucket
#define BKT_NODES 256
#define MAXB 512            // scan width (B = 391 <= 512)
#define CAP 8192            // fixed region capacity per bucket (mean 4096 + 64 sigma)
#define GROWS 128           // rows per fused block-tile (512 thr, Wl amortized)
#define SSTR 68             // padded LDS row stride for S tile

typedef unsigned int u32;

// bf16 helpers
__device__ __forceinline__ u32 bfr(float v) {          // fp32 -> bf16 bits (RNE)
    u32 x = __float_as_uint(v);
    return (x + 0x7fffu + ((x >> 16) & 1u)) >> 16;
}
__device__ __forceinline__ u32 pack2(float lo, float hi) { return bfr(lo) | (bfr(hi) << 16); }
__device__ __forceinline__ float blo(u32 w) { return __uint_as_float(w << 16); }
__device__ __forceinline__ float bhi(u32 w) { return __uint_as_float(w & 0xffff0000u); }

// ---- partition: chunk -> in-LDS counting sort -> contiguous runs into ------
// fixed-capacity bucket regions. Packed word: (dst & 255) << 17 | src.
// cursor[b] counts edges per bucket (memset-0 init); region base = b*CAP.

__global__ void partition(const int* __restrict__ src, const int* __restrict__ dst,
                          int* __restrict__ cursor, int* __restrict__ packed,
                          int nE, int B) {
    __shared__ int hist[MAXB];           // counts, then local cursor
    __shared__ int delta[MAXB];          // global_run_pos - local_excl
    __shared__ int wsum[16];             // per-wave scan partials
    __shared__ int sorted[CHUNK];
    __shared__ unsigned short sortedb[CHUNK];
    int t = threadIdx.x;  // 1024 threads
    int i0 = blockIdx.x * CHUNK;
    int cn = min(CHUNK, nE - i0);

    if (t < MAXB) hist[t] = 0;
    __syncthreads();
    for (int i = t; i < cn; i += 1024) atomicAdd(&hist[dst[i0 + i] >> BKT_SHIFT], 1);
    __syncthreads();

    // wave-level inclusive scan over MAXB=512 entries (first 8 waves)
    int v = (t < MAXB) ? hist[t] : 0;
    int incl = v;
#pragma unroll
    for (int off = 1; off < 64; off <<= 1) {
        int u = __shfl_up(incl, off, 64);
        if ((t & 63) >= off) incl += u;
    }
    if ((t & 63) == 63 && t < MAXB) wsum[t >> 6] = incl;
    __syncthreads();
    if (t < MAXB) {
        int wp = 0;
        int w = t >> 6;            // wave id 0..7
        for (int k = 0; k < w; ++k) wp += wsum[k];
        incl += wp;
        int excl = incl - v;       // exclusive prefix of bucket t
        int rb = 0;
        if (t < B && v > 0) rb = atomicAdd(&cursor[t], v);
        delta[t] = (t * CAP + rb) - excl;
        hist[t] = excl;            // local cursor for the LDS scatter
    }
    __syncthreads();

    for (int i = t; i < cn; i += 1024) {
        int d = dst[i0 + i];
        int b = d >> BKT_SHIFT;
        int pp = atomicAdd(&hist[b], 1);
        sorted[pp]  = ((d & (BKT_NODES - 1)) << 17) | src[i0 + i];
        sortedb[pp] = (unsigned short)b;
    }
    __syncthreads();

    for (int i = t; i < cn; i += 1024) {
        packed[delta[sortedb[i]] + i] = sorted[i];
    }
}

// ---- bucket finalize: in-block bucket_base + per-node CSR + bf16 prescale --
// One block (512 threads) per 256-node bucket. cursor[b] = edge count.

__global__ void bucket_csr(const int* __restrict__ packed, const int* __restrict__ cursor,
                           int* __restrict__ row_ptr, float* __restrict__ dinv,
                           int* __restrict__ adj, const float* __restrict__ x,
                           u32* __restrict__ xp, int n, int B) {
    __shared__ int s[512];
    __shared__ int hn[BKT_NODES];
    __shared__ int cur[BKT_NODES];
    __shared__ float dv[BKT_NODES];
    __shared__ int wsum[8];
    __shared__ int base_s;
    int t = threadIdx.x;  // 512 threads
    int b = blockIdx.x;
    int rlo = b * CAP;
    int mycnt = min(cursor[b], CAP);

    // bucket_base[b] = sum of counts of buckets < b
    int partial = (t < b) ? cursor[t] : 0;   // b <= 390 < 512
    s[t] = partial;
    __syncthreads();
    for (int off = 256; off > 0; off >>= 1) {
        if (t < off) s[t] += s[t + off];
        __syncthreads();
    }
    if (t == 0) base_s = s[0];
    __syncthreads();
    int base = base_s;
    if (b == B - 1 && t == 0) row_ptr[n] = base + mycnt;   // == nE

    // per-node histogram (512 threads into 256 counters)
    if (t < BKT_NODES) hn[t] = 0;
    __syncthreads();
    for (int i = t; i < mycnt; i += 512) atomicAdd(&hn[packed[rlo + i] >> 17], 1);
    __syncthreads();

    // wave-level inclusive scan over 256 entries (first 4 waves)
    int v = (t < BKT_NODES) ? hn[t] : 0;
    int incl = v;
#pragma unroll
    for (int off = 1; off < 64; off <<= 1) {
        int u = __shfl_up(incl, off, 64);
        if ((t & 63) >= off) incl += u;
    }
    if ((t & 63) == 63 && t < BKT_NODES) wsum[t >> 6] = incl;
    __syncthreads();
    if (t < BKT_NODES) {
        int wp = 0;
        int w = t >> 6;            // wave id 0..3
        for (int k = 0; k < w; ++k) wp += wsum[k];
        incl += wp;
        int gbeg = base + incl - v;   // global exclusive prefix
        int node = (b << BKT_SHIFT) + t;
        float di = rsqrtf(1.0f + (float)v);   // self-loop included
        if (node < n) {
            row_ptr[node] = gbeg;
            dinv[node] = di;
        }
        dv[t] = di;
        cur[t] = gbeg;
    }
    __syncthreads();

    for (int i = t; i < mycnt; i += 512) {
        int w = packed[rlo + i];
        int pos = atomicAdd(&cur[w >> 17], 1);
        adj[pos] = w & 0x1FFFF;
    }

    // fused bf16 prescale: item i -> (row = i>>3, feature block 8*(i&7))
    int nbase = b << BKT_SHIFT;
    for (int i = t; i < BKT_NODES * 8; i += 512) {
        int row = i >> 3, fb = i & 7;
        int nd = nbase + row;
        if (nd < n) {
            float d2 = dv[row];
            const float4* xr = (const float4*)(x + (size_t)nd * D + 8 * fb);
            float4 v0 = xr[0], v1 = xr[1];
            uint4 w;
            w.x = pack2(d2 * v0.x, d2 * v0.y);
            w.y = pack2(d2 * v0.z, d2 * v0.w);
            w.z = pack2(d2 * v1.x, d2 * v1.y);
            w.w = pack2(d2 * v1.z, d2 * v1.w);
            ((uint4*)(xp + (size_t)nd * (D / 2)))[fb] = w;
        }
    }
}

// ---- fused gather + tiled GEMM ---------------------------------------------
// Per block: 128-row output tile, 512 threads (8 waves).
// LDS = Wl 16KB + Sl 34KB = 50KB -> 3 blocks/CU -> 24 waves/CU (was 16).
// Phase 1 (gather): 8 waves x 2 rounds x 8 nodes; 16-wide neighbor batches.
// Phase 2 (GEMM):   out-tile = epi(dinv * (Sl @ W))
// MODE 0: outb(bf16) = dinv * relu(dinv * y)   (next layer's pre-scaled input)
// MODE 1: outf(f32)  = dinv * y + bias         (final output)
template <int MODE>
__launch_bounds__(512, 6)
__global__ void fused(const u32* __restrict__ hp, const int* __restrict__ row_ptr,
                      const int* __restrict__ adj,
                      const float* __restrict__ W, const float* __restrict__ bias,
                      const float* __restrict__ dinv,
                      float* __restrict__ outf, u32* __restrict__ outb, int n) {
    __shared__ float Wl[D * D];          // stride 64
    __shared__ float Sl[GROWS * SSTR];   // stride 68 (pad kills pow2 conflicts)
    const int t = threadIdx.x;

    for (int i = t; i < D * D / 4; i += 512)
        ((float4*)Wl)[i] = ((const float4*)W)[i];

    const int R0 = blockIdx.x * GROWS;

    // ---- phase 1: gather into Sl --------------------------------------
    const int lane = t & 63;
    const int o = lane >> 3;   // octet = which of the wave's 8 nodes
    const int f = lane & 7;    // feature group: features 8f..8f+7
    const int wv = t >> 6;     // wave 0..7

#pragma unroll
    for (int r = 0; r < 2; ++r) {
        int row = wv * 16 + r * 8 + o;   // 0..127 within tile
        int nq = R0 + row;
        bool valid = nq < n;
        int nqc = valid ? nq : 0;
        int rb = row_ptr[nqc];
        int re = row_ptr[nqc + 1];
        int len = valid ? (re - rb) : 0;

        uint4 sw = ((const uint4*)(hp + (size_t)nqc * (D / 2)))[f];
        float acc[8];
        acc[0] = blo(sw.x); acc[1] = bhi(sw.x);
        acc[2] = blo(sw.y); acc[3] = bhi(sw.y);
        acc[4] = blo(sw.z); acc[5] = bhi(sw.z);
        acc[6] = blo(sw.w); acc[7] = bhi(sw.w);

        int lm = len;
        lm = max(lm, __shfl_xor(lm, 8, 64));
        lm = max(lm, __shfl_xor(lm, 16, 64));
        lm = max(lm, __shfl_xor(lm, 32, 64));

        for (int base = 0; base < lm; base += 16) {
            int rem = len - base;
            int ia = 0, ib = 0;
            if (f < rem)     ia = adj[rb + base + f];
            if (f + 8 < rem) ib = adj[rb + base + 8 + f];
            uint4 vv[16];
            {
                int ss[16];
#pragma unroll
                for (int u = 0; u < 8; ++u) {
                    ss[u]     = __shfl(ia, (o << 3) | u, 64);
                    ss[u + 8] = __shfl(ib, (o << 3) | u, 64);
                }
#pragma unroll
                for (int u = 0; u < 16; ++u) {
                    vv[u] = ((const uint4*)(hp + (size_t)ss[u] * (D / 2)))[f];
                }
            }
#pragma unroll
            for (int u = 0; u < 16; ++u) {
                float m = (u < rem) ? 1.0f : 0.0f;
                acc[0] = fmaf(m, blo(vv[u].x), acc[0]);
                acc[1] = fmaf(m, bhi(vv[u].x), acc[1]);
                acc[2] = fmaf(m, blo(vv[u].y), acc[2]);
                acc[3] = fmaf(m, bhi(vv[u].y), acc[3]);
                acc[4] = fmaf(m, blo(vv[u].z), acc[4]);
                acc[5] = fmaf(m, bhi(vv[u].z), acc[5]);
                acc[6] = fmaf(m, blo(vv[u].w), acc[6]);
                acc[7] = fmaf(m, bhi(vv[u].w), acc[7]);
            }
        }
        // deposit straight into the GEMM's LDS tile (values finite even for
        // padded rows; epilogue masks stores for row >= n)
        *(float4*)&Sl[row * SSTR + 8 * f]     = make_float4(acc[0], acc[1], acc[2], acc[3]);
        *(float4*)&Sl[row * SSTR + 8 * f + 4] = make_float4(acc[4], acc[5], acc[6], acc[7]);
    }
    __syncthreads();

    // ---- phase 2: register-blocked GEMM on the LDS tile ----------------
    const int cg = t & 15;   // cols 4cg..4cg+3
    const int rg = t >> 4;   // rows 4rg..4rg+3 (0..31)

    float4 acc0 = make_float4(0.f, 0.f, 0.f, 0.f);
    float4 acc1 = make_float4(0.f, 0.f, 0.f, 0.f);
    float4 acc2 = make_float4(0.f, 0.f, 0.f, 0.f);
    float4 acc3 = make_float4(0.f, 0.f, 0.f, 0.f);

#pragma unroll 4
    for (int k = 0; k < D; k += 4) {
        float4 a0 = *(const float4*)&Sl[(4 * rg + 0) * SSTR + k];
        float4 a1 = *(const float4*)&Sl[(4 * rg + 1) * SSTR + k];
        float4 a2 = *(const float4*)&Sl[(4 * rg + 2) * SSTR + k];
        float4 a3 = *(const float4*)&Sl[(4 * rg + 3) * SSTR + k];
        float4 w0 = *(const float4*)&Wl[(k + 0) * D + 4 * cg];
        float4 w1 = *(const float4*)&Wl[(k + 1) * D + 4 * cg];
        float4 w2 = *(const float4*)&Wl[(k + 2) * D + 4 * cg];
        float4 w3 = *(const float4*)&Wl[(k + 3) * D + 4 * cg];
#define MAC(ACC, A)                                                        \
        ACC.x = fmaf(A.x, w0.x, fmaf(A.y, w1.x, fmaf(A.z, w2.x, fmaf(A.w, w3.x, ACC.x)))); \
        ACC.y = fmaf(A.x, w0.y, fmaf(A.y, w1.y, fmaf(A.z, w2.y, fmaf(A.w, w3.y, ACC.y)))); \
        ACC.z = fmaf(A.x, w0.z, fmaf(A.y, w1.z, fmaf(A.z, w2.z, fmaf(A.w, w3.z, ACC.z)))); \
        ACC.w = fmaf(A.x, w0.w, fmaf(A.y, w1.w, fmaf(A.z, w2.w, fmaf(A.w, w3.w, ACC.w))))
        MAC(acc0, a0);
        MAC(acc1, a1);
        MAC(acc2, a2);
        MAC(acc3, a3);
#undef MAC
    }

    const float4 bv = (MODE == 1) ? ((const float4*)bias)[cg]
                                  : make_float4(0.f, 0.f, 0.f, 0.f);
    float4 accs[4] = {acc0, acc1, acc2, acc3};
#pragma unroll
    for (int r = 0; r < 4; ++r) {
        int row = R0 + 4 * rg + r;
        if (row >= n) break;
        float dn = dinv[row];
        float4 y = accs[r];
        if (MODE == 0) {
            float o0 = dn * fmaxf(dn * y.x, 0.f);
            float o1 = dn * fmaxf(dn * y.y, 0.f);
            float o2 = dn * fmaxf(dn * y.z, 0.f);
            float o3 = dn * fmaxf(dn * y.w, 0.f);
            uint2 w2o;
            w2o.x = pack2(o0, o1);
            w2o.y = pack2(o2, o3);
            ((uint2*)(outb + (size_t)row * (D / 2)))[cg] = w2o;
        } else {
            float4 oo;
            oo.x = fmaf(dn, y.x, bv.x);
            oo.y = fmaf(dn, y.y, bv.y);
            oo.z = fmaf(dn, y.z, bv.z);
            oo.w = fmaf(dn, y.w, bv.w);
            ((float4*)(outf + (size_t)row * D))[cg] = oo;
        }
    }
}

// ---- launch ----------------------------------------------------------------

extern "C" void kernel_launch(void* const* d_in, const int* in_sizes, int n_in,
                              void* d_out, int out_size, void* d_ws, size_t ws_size,
                              hipStream_t stream) {
    const float* x  = (const float*)d_in[0];
    const float* W1 = (const float*)d_in[1];
    const float* W2 = (const float*)d_in[2];
    const float* b2 = (const float*)d_in[3];
    const int*   ei = (const int*)d_in[4];

    int n  = in_sizes[0] / D;   // 100000
    int nE = in_sizes[4] / 2;   // 1600000
    const int* src = ei;        // message source
    const int* dst = ei + nE;   // aggregation target

    int B = (n + BKT_NODES - 1) >> BKT_SHIFT;  // 391 buckets

    // workspace layout (aligned to 256B):
    //   row_ptr | dinv | cursor [MAXB] | adj [nE] | packed [(B+1)*CAP] |
    //   F0 [n*D/2 u32, bf16] | F1 [n*D/2 u32, bf16]
    auto align = [](size_t v) { return (v + 255) & ~(size_t)255; };
    char* ws = (char*)d_ws;
    size_t off = 0;
    int* row_ptr = (int*)(ws + off);   off += align((size_t)(n + 1) * 4);
    float* dinv  = (float*)(ws + off); off += align((size_t)n * 4);
    int* cursor  = (int*)(ws + off);   off += align((size_t)MAXB * 4);
    int* adj     = (int*)(ws + off);   off += align((size_t)nE * 4);
    int* packed  = (int*)(ws + off);   off += align((size_t)(B + 1) * CAP * 4);
    u32* F0      = (u32*)(ws + off);   off += align((size_t)n * (D / 2) * 4);
    u32* F1      = (u32*)(ws + off);
    float* out = (float*)d_out;

    int nchunks = (nE + CHUNK - 1) / CHUNK;  // 391

    // CSR build: memset + 2 dispatches
    hipMemsetAsync(cursor, 0, (size_t)MAXB * 4, stream);
    partition<<<nchunks, 1024, 0, stream>>>(src, dst, cursor, packed, nE, B);
    bucket_csr<<<B, 512, 0, stream>>>(packed, cursor, row_ptr, dinv, adj, x, F0, n, B);

    int gblocks = (n + GROWS - 1) / GROWS;  // 782

    // layer 1: F1 = bf16(dinv*relu(dinv*(gather(F0)@W1)))   (separate buffer:
    // gather reads F0 cross-block while we write -> no in-place)
    fused<0><<<gblocks, 512, 0, stream>>>(F0, row_ptr, adj, W1, nullptr, dinv, nullptr, F1, n);

    // layer 2: out = dinv*(gather(F1)@W2) + b2
    fused<1><<<gblocks, 512, 0, stream>>>(F1, row_ptr, adj, W2, b2, dinv, out, nullptr, n);
}

// Round 7
// 215.389 us; speedup vs baseline: 1.4091x; 1.4091x over previous
//
#include <hip/hip_runtime.h>

#define D 64
#define CHUNK 4096          // edges per partition block (391 blocks, 1024 thr -> 4 passes)
#define BKT_SHIFT 8         // 256 nodes per bucket
#define BKT_NODES 256
#define MAXB 512            // scan width (B = 391 <= 512)
#define CAP 8192            // fixed region capacity per bucket (mean 4096 + 64 sigma)
#define GROWS 64            // rows per fused block-tile
#define SSTR 64             // Sl row stride; Wl+Sl = 32KB exactly -> 5 blocks/CU

typedef unsigned int u32;

// bf16 helpers
__device__ __forceinline__ u32 bfr(float v) {          // fp32 -> bf16 bits (RNE)
    u32 x = __float_as_uint(v);
    return (x + 0x7fffu + ((x >> 16) & 1u)) >> 16;
}
__device__ __forceinline__ u32 pack2(float lo, float hi) { return bfr(lo) | (bfr(hi) << 16); }
__device__ __forceinline__ float blo(u32 w) { return __uint_as_float(w << 16); }
__device__ __forceinline__ float bhi(u32 w) { return __uint_as_float(w & 0xffff0000u); }

// ---- partition: chunk -> in-LDS counting sort -> contiguous runs into ------
// fixed-capacity bucket regions. Packed word: (dst & 255) << 17 | src.
// cursor[b] counts edges per bucket (memset-0 init); region base = b*CAP.

__global__ void partition(const int* __restrict__ src, const int* __restrict__ dst,
                          int* __restrict__ cursor, int* __restrict__ packed,
                          int nE, int B) {
    __shared__ int hist[MAXB];           // counts, then local cursor
    __shared__ int delta[MAXB];          // global_run_pos - local_excl
    __shared__ int wsum[16];             // per-wave scan partials
    __shared__ int sorted[CHUNK];
    __shared__ unsigned short sortedb[CHUNK];
    int t = threadIdx.x;  // 1024 threads
    int i0 = blockIdx.x * CHUNK;
    int cn = min(CHUNK, nE - i0);

    if (t < MAXB) hist[t] = 0;
    __syncthreads();
    for (int i = t; i < cn; i += 1024) atomicAdd(&hist[dst[i0 + i] >> BKT_SHIFT], 1);
    __syncthreads();

    // wave-level inclusive scan over MAXB=512 entries (first 8 waves)
    int v = (t < MAXB) ? hist[t] : 0;
    int incl = v;
#pragma unroll
    for (int off = 1; off < 64; off <<= 1) {
        int u = __shfl_up(incl, off, 64);
        if ((t & 63) >= off) incl += u;
    }
    if ((t & 63) == 63 && t < MAXB) wsum[t >> 6] = incl;
    __syncthreads();
    if (t < MAXB) {
        int wp = 0;
        int w = t >> 6;            // wave id 0..7
        for (int k = 0; k < w; ++k) wp += wsum[k];
        incl += wp;
        int excl = incl - v;       // exclusive prefix of bucket t
        int rb = 0;
        if (t < B && v > 0) rb = atomicAdd(&cursor[t], v);
        delta[t] = (t * CAP + rb) - excl;
        hist[t] = excl;            // local cursor for the LDS scatter
    }
    __syncthreads();

    for (int i = t; i < cn; i += 1024) {
        int d = dst[i0 + i];
        int b = d >> BKT_SHIFT;
        int pp = atomicAdd(&hist[b], 1);
        sorted[pp]  = ((d & (BKT_NODES - 1)) << 17) | src[i0 + i];
        sortedb[pp] = (unsigned short)b;
    }
    __syncthreads();

    for (int i = t; i < cn; i += 1024) {
        packed[delta[sortedb[i]] + i] = sorted[i];
    }
}

// ---- bucket finalize: in-block bucket_base + per-node CSR + bf16 prescale --
// One block (512 threads) per 256-node bucket. cursor[b] = edge count.

__global__ void bucket_csr(const int* __restrict__ packed, const int* __restrict__ cursor,
                           int* __restrict__ row_ptr, float* __restrict__ dinv,
                           int* __restrict__ adj, const float* __restrict__ x,
                           u32* __restrict__ xp, int n, int B) {
    __shared__ int s[512];
    __shared__ int hn[BKT_NODES];
    __shared__ int cur[BKT_NODES];
    __shared__ float dv[BKT_NODES];
    __shared__ int wsum[8];
    __shared__ int base_s;
    int t = threadIdx.x;  // 512 threads
    int b = blockIdx.x;
    int rlo = b * CAP;
    int mycnt = min(cursor[b], CAP);

    // bucket_base[b] = sum of counts of buckets < b
    int partial = (t < b) ? cursor[t] : 0;   // b <= 390 < 512
    s[t] = partial;
    __syncthreads();
    for (int off = 256; off > 0; off >>= 1) {
        if (t < off) s[t] += s[t + off];
        __syncthreads();
    }
    if (t == 0) base_s = s[0];
    __syncthreads();
    int base = base_s;
    if (b == B - 1 && t == 0) row_ptr[n] = base + mycnt;   // == nE

    // per-node histogram (512 threads into 256 counters)
    if (t < BKT_NODES) hn[t] = 0;
    __syncthreads();
    for (int i = t; i < mycnt; i += 512) atomicAdd(&hn[packed[rlo + i] >> 17], 1);
    __syncthreads();

    // wave-level inclusive scan over 256 entries (first 4 waves)
    int v = (t < BKT_NODES) ? hn[t] : 0;
    int incl = v;
#pragma unroll
    for (int off = 1; off < 64; off <<= 1) {
        int u = __shfl_up(incl, off, 64);
        if ((t & 63) >= off) incl += u;
    }
    if ((t & 63) == 63 && t < BKT_NODES) wsum[t >> 6] = incl;
    __syncthreads();
    if (t < BKT_NODES) {
        int wp = 0;
        int w = t >> 6;            // wave id 0..3
        for (int k = 0; k < w; ++k) wp += wsum[k];
        incl += wp;
        int gbeg = base + incl - v;   // global exclusive prefix
        int node = (b << BKT_SHIFT) + t;
        float di = rsqrtf(1.0f + (float)v);   // self-loop included
        if (node < n) {
            row_ptr[node] = gbeg;
            dinv[node] = di;
        }
        dv[t] = di;
        cur[t] = gbeg;
    }
    __syncthreads();

    for (int i = t; i < mycnt; i += 512) {
        int w = packed[rlo + i];
        int pos = atomicAdd(&cur[w >> 17], 1);
        adj[pos] = w & 0x1FFFF;
    }

    // fused bf16 prescale: item i -> (row = i>>3, feature block 8*(i&7))
    int nbase = b << BKT_SHIFT;
    for (int i = t; i < BKT_NODES * 8; i += 512) {
        int row = i >> 3, fb = i & 7;
        int nd = nbase + row;
        if (nd < n) {
            float d2 = dv[row];
            const float4* xr = (const float4*)(x + (size_t)nd * D + 8 * fb);
            float4 v0 = xr[0], v1 = xr[1];
            uint4 w;
            w.x = pack2(d2 * v0.x, d2 * v0.y);
            w.y = pack2(d2 * v0.z, d2 * v0.w);
            w.z = pack2(d2 * v1.x, d2 * v1.y);
            w.w = pack2(d2 * v1.z, d2 * v1.w);
            ((uint4*)(xp + (size_t)nd * (D / 2)))[fb] = w;
        }
    }
}

// ---- fused gather + tiled GEMM ---------------------------------------------
// Per block: 64-row output tile, 256 threads (R5 proven shape).
// LDS = Wl 16KB + Sl 16KB = 32KB exactly -> 5 blocks/CU -> 20 waves/CU.
// VGPR budget: launch_bounds(256,5) caps at 102 >= the 64 the compiler uses
// (R5-measured); do NOT raise waves further or vv[16] spills (R6 lesson).
// Phase 1 (gather): 4 waves x 2 rounds x 8 nodes; 16-wide neighbor batches.
// Phase 2 (GEMM):   out-tile = epi(dinv * (Sl @ W))
// MODE 0: outb(bf16) = dinv * relu(dinv * y)   (next layer's pre-scaled input)
// MODE 1: outf(f32)  = dinv * y + bias         (final output)
template <int MODE>
__launch_bounds__(256, 5)
__global__ void fused(const u32* __restrict__ hp, const int* __restrict__ row_ptr,
                      const int* __restrict__ adj,
                      const float* __restrict__ W, const float* __restrict__ bias,
                      const float* __restrict__ dinv,
                      float* __restrict__ outf, u32* __restrict__ outb, int n) {
    __shared__ float Wl[D * D];          // stride 64
    __shared__ float Sl[GROWS * SSTR];   // stride 64 (32KB total -> occupancy)
    const int t = threadIdx.x;

    for (int i = t; i < D * D / 4; i += 256)
        ((float4*)Wl)[i] = ((const float4*)W)[i];

    const int R0 = blockIdx.x * GROWS;

    // ---- phase 1: gather into Sl --------------------------------------
    const int lane = t & 63;
    const int o = lane >> 3;   // octet = which of the wave's 8 nodes
    const int f = lane & 7;    // feature group: features 8f..8f+7
    const int wv = t >> 6;     // wave 0..3

#pragma unroll
    for (int r = 0; r < 2; ++r) {
        int row = wv * 16 + r * 8 + o;   // 0..63 within tile
        int nq = R0 + row;
        bool valid = nq < n;
        int nqc = valid ? nq : 0;
        int rb = row_ptr[nqc];
        int re = row_ptr[nqc + 1];
        int len = valid ? (re - rb) : 0;

        uint4 sw = ((const uint4*)(hp + (size_t)nqc * (D / 2)))[f];
        float acc[8];
        acc[0] = blo(sw.x); acc[1] = bhi(sw.x);
        acc[2] = blo(sw.y); acc[3] = bhi(sw.y);
        acc[4] = blo(sw.z); acc[5] = bhi(sw.z);
        acc[6] = blo(sw.w); acc[7] = bhi(sw.w);

        int lm = len;
        lm = max(lm, __shfl_xor(lm, 8, 64));
        lm = max(lm, __shfl_xor(lm, 16, 64));
        lm = max(lm, __shfl_xor(lm, 32, 64));

        for (int base = 0; base < lm; base += 16) {
            int rem = len - base;
            int ia = 0, ib = 0;
            if (f < rem)     ia = adj[rb + base + f];
            if (f + 8 < rem) ib = adj[rb + base + 8 + f];
            uint4 vv[16];
            {
                int ss[16];
#pragma unroll
                for (int u = 0; u < 8; ++u) {
                    ss[u]     = __shfl(ia, (o << 3) | u, 64);
                    ss[u + 8] = __shfl(ib, (o << 3) | u, 64);
                }
#pragma unroll
                for (int u = 0; u < 16; ++u) {
                    vv[u] = ((const uint4*)(hp + (size_t)ss[u] * (D / 2)))[f];
                }
            }
#pragma unroll
            for (int u = 0; u < 16; ++u) {
                float m = (u < rem) ? 1.0f : 0.0f;
                acc[0] = fmaf(m, blo(vv[u].x), acc[0]);
                acc[1] = fmaf(m, bhi(vv[u].x), acc[1]);
                acc[2] = fmaf(m, blo(vv[u].y), acc[2]);
                acc[3] = fmaf(m, bhi(vv[u].y), acc[3]);
                acc[4] = fmaf(m, blo(vv[u].z), acc[4]);
                acc[5] = fmaf(m, bhi(vv[u].z), acc[5]);
                acc[6] = fmaf(m, blo(vv[u].w), acc[6]);
                acc[7] = fmaf(m, bhi(vv[u].w), acc[7]);
            }
        }
        // deposit straight into the GEMM's LDS tile (values finite even for
        // padded rows; epilogue masks stores for row >= n)
        *(float4*)&Sl[row * SSTR + 8 * f]     = make_float4(acc[0], acc[1], acc[2], acc[3]);
        *(float4*)&Sl[row * SSTR + 8 * f + 4] = make_float4(acc[4], acc[5], acc[6], acc[7]);
    }
    __syncthreads();

    // ---- phase 2: register-blocked GEMM on the LDS tile ----------------
    const int cg = t & 15;   // cols 4cg..4cg+3
    const int rg = t >> 4;   // rows 4rg..4rg+3

    float4 acc0 = make_float4(0.f, 0.f, 0.f, 0.f);
    float4 acc1 = make_float4(0.f, 0.f, 0.f, 0.f);
    float4 acc2 = make_float4(0.f, 0.f, 0.f, 0.f);
    float4 acc3 = make_float4(0.f, 0.f, 0.f, 0.f);

#pragma unroll 4
    for (int k = 0; k < D; k += 4) {
        float4 a0 = *(const float4*)&Sl[(4 * rg + 0) * SSTR + k];
        float4 a1 = *(const float4*)&Sl[(4 * rg + 1) * SSTR + k];
        float4 a2 = *(const float4*)&Sl[(4 * rg + 2) * SSTR + k];
        float4 a3 = *(const float4*)&Sl[(4 * rg + 3) * SSTR + k];
        float4 w0 = *(const float4*)&Wl[(k + 0) * D + 4 * cg];
        float4 w1 = *(const float4*)&Wl[(k + 1) * D + 4 * cg];
        float4 w2 = *(const float4*)&Wl[(k + 2) * D + 4 * cg];
        float4 w3 = *(const float4*)&Wl[(k + 3) * D + 4 * cg];
#define MAC(ACC, A)                                                        \
        ACC.x = fmaf(A.x, w0.x, fmaf(A.y, w1.x, fmaf(A.z, w2.x, fmaf(A.w, w3.x, ACC.x)))); \
        ACC.y = fmaf(A.x, w0.y, fmaf(A.y, w1.y, fmaf(A.z, w2.y, fmaf(A.w, w3.y, ACC.y)))); \
        ACC.z = fmaf(A.x, w0.z, fmaf(A.y, w1.z, fmaf(A.z, w2.z, fmaf(A.w, w3.z, ACC.z)))); \
        ACC.w = fmaf(A.x, w0.w, fmaf(A.y, w1.w, fmaf(A.z, w2.w, fmaf(A.w, w3.w, ACC.w))))
        MAC(acc0, a0);
        MAC(acc1, a1);
        MAC(acc2, a2);
        MAC(acc3, a3);
#undef MAC
    }

    const float4 bv = (MODE == 1) ? ((const float4*)bias)[cg]
                                  : make_float4(0.f, 0.f, 0.f, 0.f);
    float4 accs[4] = {acc0, acc1, acc2, acc3};
#pragma unroll
    for (int r = 0; r < 4; ++r) {
        int row = R0 + 4 * rg + r;
        if (row >= n) break;
        float dn = dinv[row];
        float4 y = accs[r];
        if (MODE == 0) {
            float o0 = dn * fmaxf(dn * y.x, 0.f);
            float o1 = dn * fmaxf(dn * y.y, 0.f);
            float o2 = dn * fmaxf(dn * y.z, 0.f);
            float o3 = dn * fmaxf(dn * y.w, 0.f);
            uint2 w2o;
            w2o.x = pack2(o0, o1);
            w2o.y = pack2(o2, o3);
            ((uint2*)(outb + (size_t)row * (D / 2)))[cg] = w2o;
        } else {
            float4 oo;
            oo.x = fmaf(dn, y.x, bv.x);
            oo.y = fmaf(dn, y.y, bv.y);
            oo.z = fmaf(dn, y.z, bv.z);
            oo.w = fmaf(dn, y.w, bv.w);
            ((float4*)(outf + (size_t)row * D))[cg] = oo;
        }
    }
}

// ---- launch ----------------------------------------------------------------

extern "C" void kernel_launch(void* const* d_in, const int* in_sizes, int n_in,
                              void* d_out, int out_size, void* d_ws, size_t ws_size,
                              hipStream_t stream) {
    const float* x  = (const float*)d_in[0];
    const float* W1 = (const float*)d_in[1];
    const float* W2 = (const float*)d_in[2];
    const float* b2 = (const float*)d_in[3];
    const int*   ei = (const int*)d_in[4];

    int n  = in_sizes[0] / D;   // 100000
    int nE = in_sizes[4] / 2;   // 1600000
    const int* src = ei;        // message source
    const int* dst = ei + nE;   // aggregation target

    int B = (n + BKT_NODES - 1) >> BKT_SHIFT;  // 391 buckets

    // workspace layout (aligned to 256B):
    //   row_ptr | dinv | cursor [MAXB] | adj [nE] | packed [(B+1)*CAP] |
    //   F0 [n*D/2 u32, bf16] | F1 [n*D/2 u32, bf16]
    auto align = [](size_t v) { return (v + 255) & ~(size_t)255; };
    char* ws = (char*)d_ws;
    size_t off = 0;
    int* row_ptr = (int*)(ws + off);   off += align((size_t)(n + 1) * 4);
    float* dinv  = (float*)(ws + off); off += align((size_t)n * 4);
    int* cursor  = (int*)(ws + off);   off += align((size_t)MAXB * 4);
    int* adj     = (int*)(ws + off);   off += align((size_t)nE * 4);
    int* packed  = (int*)(ws + off);   off += align((size_t)(B + 1) * CAP * 4);
    u32* F0      = (u32*)(ws + off);   off += align((size_t)n * (D / 2) * 4);
    u32* F1      = (u32*)(ws + off);
    float* out = (float*)d_out;

    int nchunks = (nE + CHUNK - 1) / CHUNK;  // 391

    // CSR build: memset + 2 dispatches
    hipMemsetAsync(cursor, 0, (size_t)MAXB * 4, stream);
    partition<<<nchunks, 1024, 0, stream>>>(src, dst, cursor, packed, nE, B);
    bucket_csr<<<B, 512, 0, stream>>>(packed, cursor, row_ptr, dinv, adj, x, F0, n, B);

    int gblocks = (n + GROWS - 1) / GROWS;  // 1563

    // layer 1: F1 = bf16(dinv*relu(dinv*(gather(F0)@W1)))   (separate buffer:
    // gather reads F0 cross-block while we write -> no in-place)
    fused<0><<<gblocks, 256, 0, stream>>>(F0, row_ptr, adj, W1, nullptr, dinv, nullptr, F1, n);

    // layer 2: out = dinv*(gather(F1)@W2) + b2
    fused<1><<<gblocks, 256, 0, stream>>>(F1, row_ptr, adj, W2, b2, dinv, out, nullptr, n);
}

// Round 8
// 194.145 us; speedup vs baseline: 1.5633x; 1.1094x over previous
//
#include <hip/hip_runtime.h>

#define D 64
#define CHUNK 4096          // edges per partition block (391 blocks, 1024 thr -> 4 passes)
#define BKT_SHIFT 8         // 256 nodes per bucket
#define BKT_NODES 256
#define MAXB 512            // scan width (B = 391 <= 512)
#define CAP 8192            // fixed region capacity per bucket (mean 4096 + 64 sigma)
#define GROWS 64            // rows per fused block-tile
#define SSTR 68             // padded LDS row stride; 68%32=4 spreads octet writes across banks

typedef unsigned int u32;

// bf16 helpers
__device__ __forceinline__ u32 bfr(float v) {          // fp32 -> bf16 bits (RNE)
    u32 x = __float_as_uint(v);
    return (x + 0x7fffu + ((x >> 16) & 1u)) >> 16;
}
__device__ __forceinline__ u32 pack2(float lo, float hi) { return bfr(lo) | (bfr(hi) << 16); }
__device__ __forceinline__ float blo(u32 w) { return __uint_as_float(w << 16); }
__device__ __forceinline__ float bhi(u32 w) { return __uint_as_float(w & 0xffff0000u); }

// ---- partition: chunk -> in-LDS counting sort -> contiguous runs into ------
// fixed-capacity bucket regions. Packed word: (dst & 255) << 17 | src.
// cursor[b] counts edges per bucket (memset-0 init); region base = b*CAP.
// dst is read from global ONCE (cached in dstl) -- kills the 2nd latency pass.

__global__ void partition(const int* __restrict__ src, const int* __restrict__ dst,
                          int* __restrict__ cursor, int* __restrict__ packed,
                          int nE, int B) {
    __shared__ int hist[MAXB];           // counts, then local cursor
    __shared__ int delta[MAXB];          // global_run_pos - local_excl
    __shared__ int wsum[16];             // per-wave scan partials
    __shared__ int dstl[CHUNK];          // cached dst words (read global once)
    __shared__ int sorted[CHUNK];
    __shared__ unsigned short sortedb[CHUNK];
    int t = threadIdx.x;  // 1024 threads
    int i0 = blockIdx.x * CHUNK;
    int cn = min(CHUNK, nE - i0);

    if (t < MAXB) hist[t] = 0;
    __syncthreads();
    for (int i = t; i < cn; i += 1024) {
        int d = dst[i0 + i];
        dstl[i] = d;
        atomicAdd(&hist[d >> BKT_SHIFT], 1);
    }
    __syncthreads();

    // wave-level inclusive scan over MAXB=512 entries (first 8 waves)
    int v = (t < MAXB) ? hist[t] : 0;
    int incl = v;
#pragma unroll
    for (int off = 1; off < 64; off <<= 1) {
        int u = __shfl_up(incl, off, 64);
        if ((t & 63) >= off) incl += u;
    }
    if ((t & 63) == 63 && t < MAXB) wsum[t >> 6] = incl;
    __syncthreads();
    if (t < MAXB) {
        int wp = 0;
        int w = t >> 6;            // wave id 0..7
        for (int k = 0; k < w; ++k) wp += wsum[k];
        incl += wp;
        int excl = incl - v;       // exclusive prefix of bucket t
        int rb = 0;
        if (t < B && v > 0) rb = atomicAdd(&cursor[t], v);
        delta[t] = (t * CAP + rb) - excl;
        hist[t] = excl;            // local cursor for the LDS scatter
    }
    __syncthreads();

    for (int i = t; i < cn; i += 1024) {
        int d = dstl[i];
        int b = d >> BKT_SHIFT;
        int pp = atomicAdd(&hist[b], 1);
        sorted[pp]  = ((d & (BKT_NODES - 1)) << 17) | src[i0 + i];
        sortedb[pp] = (unsigned short)b;
    }
    __syncthreads();

    for (int i = t; i < cn; i += 1024) {
        packed[delta[sortedb[i]] + i] = sorted[i];
    }
}

// ---- bucket finalize: in-block bucket_base + per-node CSR + bf16 prescale --
// One block (1024 threads) per 256-node bucket. cursor[b] = edge count.
// packed is read from global ONCE (cached in pk) -- kills the 2nd latency pass.

__global__ void bucket_csr(const int* __restrict__ packed, const int* __restrict__ cursor,
                           int* __restrict__ row_ptr, float* __restrict__ dinv,
                           int* __restrict__ adj, const float* __restrict__ x,
                           u32* __restrict__ xp, int n, int B) {
    __shared__ int s[1024];
    __shared__ int hn[BKT_NODES];
    __shared__ int cur[BKT_NODES];
    __shared__ float dv[BKT_NODES];
    __shared__ int wsum[4];
    __shared__ int base_s;
    __shared__ int pk[CAP];              // cached packed words (read global once)
    int t = threadIdx.x;  // 1024 threads
    int b = blockIdx.x;
    int rlo = b * CAP;
    int mycnt = min(cursor[b], CAP);

    // bucket_base[b] = sum of counts of buckets < b
    int partial = (t < b) ? cursor[t] : 0;   // b <= 390 < 1024
    s[t] = partial;
    __syncthreads();
    for (int off = 512; off > 0; off >>= 1) {
        if (t < off) s[t] += s[t + off];
        __syncthreads();
    }
    if (t == 0) base_s = s[0];
    __syncthreads();
    int base = base_s;
    if (b == B - 1 && t == 0) row_ptr[n] = base + mycnt;   // == nE

    // per-node histogram + pk cache fill (one global pass)
    if (t < BKT_NODES) hn[t] = 0;
    __syncthreads();
    for (int i = t; i < mycnt; i += 1024) {
        int w = packed[rlo + i];
        pk[i] = w;
        atomicAdd(&hn[w >> 17], 1);
    }
    __syncthreads();

    // wave-level inclusive scan over 256 entries (first 4 waves)
    int v = (t < BKT_NODES) ? hn[t] : 0;
    int incl = v;
#pragma unroll
    for (int off = 1; off < 64; off <<= 1) {
        int u = __shfl_up(incl, off, 64);
        if ((t & 63) >= off) incl += u;
    }
    if ((t & 63) == 63 && t < BKT_NODES) wsum[t >> 6] = incl;
    __syncthreads();
    if (t < BKT_NODES) {
        int wp = 0;
        int w = t >> 6;            // wave id 0..3
        for (int k = 0; k < w; ++k) wp += wsum[k];
        incl += wp;
        int gbeg = base + incl - v;   // global exclusive prefix
        int node = (b << BKT_SHIFT) + t;
        float di = rsqrtf(1.0f + (float)v);   // self-loop included
        if (node < n) {
            row_ptr[node] = gbeg;
            dinv[node] = di;
        }
        dv[t] = di;
        cur[t] = gbeg;
    }
    __syncthreads();

    for (int i = t; i < mycnt; i += 1024) {
        int w = pk[i];
        int pos = atomicAdd(&cur[w >> 17], 1);
        adj[pos] = w & 0x1FFFF;
    }

    // fused bf16 prescale: item i -> (row = i>>3, feature block 8*(i&7))
    int nbase = b << BKT_SHIFT;
    for (int i = t; i < BKT_NODES * 8; i += 1024) {
        int row = i >> 3, fb = i & 7;
        int nd = nbase + row;
        if (nd < n) {
            float d2 = dv[row];
            const float4* xr = (const float4*)(x + (size_t)nd * D + 8 * fb);
            float4 v0 = xr[0], v1 = xr[1];
            uint4 w;
            w.x = pack2(d2 * v0.x, d2 * v0.y);
            w.y = pack2(d2 * v0.z, d2 * v0.w);
            w.z = pack2(d2 * v1.x, d2 * v1.y);
            w.w = pack2(d2 * v1.z, d2 * v1.w);
            ((uint4*)(xp + (size_t)nd * (D / 2)))[fb] = w;
        }
    }
}

// ---- fused gather + tiled GEMM (R5 proven shape -- DO NOT TOUCH) -----------
// Per block: 64-row output tile, 256 threads, VGPR 64, LDS 33792, 4 blocks/CU.
// Phase 1 (gather): 4 waves x 2 rounds x 8 nodes; 16-wide neighbor batches.
// Phase 2 (GEMM):   out-tile = epi(dinv * (Sl @ W))
// MODE 0: outb(bf16) = dinv * relu(dinv * y)   (next layer's pre-scaled input)
// MODE 1: outf(f32)  = dinv * y + bias         (final output)
template <int MODE>
__launch_bounds__(256, 4)
__global__ void fused(const u32* __restrict__ hp, const int* __restrict__ row_ptr,
                      const int* __restrict__ adj,
                      const float* __restrict__ W, const float* __restrict__ bias,
                      const float* __restrict__ dinv,
                      float* __restrict__ outf, u32* __restrict__ outb, int n) {
    __shared__ float Wl[D * D];          // stride 64
    __shared__ float Sl[GROWS * SSTR];   // stride 68 (pad kills pow2 conflicts)
    const int t = threadIdx.x;

    for (int i = t; i < D * D / 4; i += 256)
        ((float4*)Wl)[i] = ((const float4*)W)[i];

    const int R0 = blockIdx.x * GROWS;

    // ---- phase 1: gather into Sl --------------------------------------
    const int lane = t & 63;
    const int o = lane >> 3;   // octet = which of the wave's 8 nodes
    const int f = lane & 7;    // feature group: features 8f..8f+7
    const int wv = t >> 6;     // wave 0..3

#pragma unroll
    for (int r = 0; r < 2; ++r) {
        int row = wv * 16 + r * 8 + o;   // 0..63 within tile
        int nq = R0 + row;
        bool valid = nq < n;
        int nqc = valid ? nq : 0;
        int rb = row_ptr[nqc];
        int re = row_ptr[nqc + 1];
        int len = valid ? (re - rb) : 0;

        uint4 sw = ((const uint4*)(hp + (size_t)nqc * (D / 2)))[f];
        float acc[8];
        acc[0] = blo(sw.x); acc[1] = bhi(sw.x);
        acc[2] = blo(sw.y); acc[3] = bhi(sw.y);
        acc[4] = blo(sw.z); acc[5] = bhi(sw.z);
        acc[6] = blo(sw.w); acc[7] = bhi(sw.w);

        int lm = len;
        lm = max(lm, __shfl_xor(lm, 8, 64));
        lm = max(lm, __shfl_xor(lm, 16, 64));
        lm = max(lm, __shfl_xor(lm, 32, 64));

        for (int base = 0; base < lm; base += 16) {
            int rem = len - base;
            int ia = 0, ib = 0;
            if (f < rem)     ia = adj[rb + base + f];
            if (f + 8 < rem) ib = adj[rb + base + 8 + f];
            uint4 vv[16];
            {
                int ss[16];
#pragma unroll
                for (int u = 0; u < 8; ++u) {
                    ss[u]     = __shfl(ia, (o << 3) | u, 64);
                    ss[u + 8] = __shfl(ib, (o << 3) | u, 64);
                }
#pragma unroll
                for (int u = 0; u < 16; ++u) {
                    vv[u] = ((const uint4*)(hp + (size_t)ss[u] * (D / 2)))[f];
                }
            }
#pragma unroll
            for (int u = 0; u < 16; ++u) {
                float m = (u < rem) ? 1.0f : 0.0f;
                acc[0] = fmaf(m, blo(vv[u].x), acc[0]);
                acc[1] = fmaf(m, bhi(vv[u].x), acc[1]);
                acc[2] = fmaf(m, blo(vv[u].y), acc[2]);
                acc[3] = fmaf(m, bhi(vv[u].y), acc[3]);
                acc[4] = fmaf(m, blo(vv[u].z), acc[4]);
                acc[5] = fmaf(m, bhi(vv[u].z), acc[5]);
                acc[6] = fmaf(m, blo(vv[u].w), acc[6]);
                acc[7] = fmaf(m, bhi(vv[u].w), acc[7]);
            }
        }
        // deposit straight into the GEMM's LDS tile (values finite even for
        // padded rows; epilogue masks stores for row >= n)
        *(float4*)&Sl[row * SSTR + 8 * f]     = make_float4(acc[0], acc[1], acc[2], acc[3]);
        *(float4*)&Sl[row * SSTR + 8 * f + 4] = make_float4(acc[4], acc[5], acc[6], acc[7]);
    }
    __syncthreads();

    // ---- phase 2: register-blocked GEMM on the LDS tile ----------------
    const int cg = t & 15;   // cols 4cg..4cg+3
    const int rg = t >> 4;   // rows 4rg..4rg+3

    float4 acc0 = make_float4(0.f, 0.f, 0.f, 0.f);
    float4 acc1 = make_float4(0.f, 0.f, 0.f, 0.f);
    float4 acc2 = make_float4(0.f, 0.f, 0.f, 0.f);
    float4 acc3 = make_float4(0.f, 0.f, 0.f, 0.f);

#pragma unroll 4
    for (int k = 0; k < D; k += 4) {
        float4 a0 = *(const float4*)&Sl[(4 * rg + 0) * SSTR + k];
        float4 a1 = *(const float4*)&Sl[(4 * rg + 1) * SSTR + k];
        float4 a2 = *(const float4*)&Sl[(4 * rg + 2) * SSTR + k];
        float4 a3 = *(const float4*)&Sl[(4 * rg + 3) * SSTR + k];
        float4 w0 = *(const float4*)&Wl[(k + 0) * D + 4 * cg];
        float4 w1 = *(const float4*)&Wl[(k + 1) * D + 4 * cg];
        float4 w2 = *(const float4*)&Wl[(k + 2) * D + 4 * cg];
        float4 w3 = *(const float4*)&Wl[(k + 3) * D + 4 * cg];
#define MAC(ACC, A)                                                        \
        ACC.x = fmaf(A.x, w0.x, fmaf(A.y, w1.x, fmaf(A.z, w2.x, fmaf(A.w, w3.x, ACC.x)))); \
        ACC.y = fmaf(A.x, w0.y, fmaf(A.y, w1.y, fmaf(A.z, w2.y, fmaf(A.w, w3.y, ACC.y)))); \
        ACC.z = fmaf(A.x, w0.z, fmaf(A.y, w1.z, fmaf(A.z, w2.z, fmaf(A.w, w3.z, ACC.z)))); \
        ACC.w = fmaf(A.x, w0.w, fmaf(A.y, w1.w, fmaf(A.z, w2.w, fmaf(A.w, w3.w, ACC.w))))
        MAC(acc0, a0);
        MAC(acc1, a1);
        MAC(acc2, a2);
        MAC(acc3, a3);
#undef MAC
    }

    const float4 bv = (MODE == 1) ? ((const float4*)bias)[cg]
                                  : make_float4(0.f, 0.f, 0.f, 0.f);
    float4 accs[4] = {acc0, acc1, acc2, acc3};
#pragma unroll
    for (int r = 0; r < 4; ++r) {
        int row = R0 + 4 * rg + r;
        if (row >= n) break;
        float dn = dinv[row];
        float4 y = accs[r];
        if (MODE == 0) {
            float o0 = dn * fmaxf(dn * y.x, 0.f);
            float o1 = dn * fmaxf(dn * y.y, 0.f);
            float o2 = dn * fmaxf(dn * y.z, 0.f);
            float o3 = dn * fmaxf(dn * y.w, 0.f);
            uint2 w2o;
            w2o.x = pack2(o0, o1);
            w2o.y = pack2(o2, o3);
            ((uint2*)(outb + (size_t)row * (D / 2)))[cg] = w2o;
        } else {
            float4 oo;
            oo.x = fmaf(dn, y.x, bv.x);
            oo.y = fmaf(dn, y.y, bv.y);
            oo.z = fmaf(dn, y.z, bv.z);
            oo.w = fmaf(dn, y.w, bv.w);
            ((float4*)(outf + (size_t)row * D))[cg] = oo;
        }
    }
}

// ---- launch ----------------------------------------------------------------

extern "C" void kernel_launch(void* const* d_in, const int* in_sizes, int n_in,
                              void* d_out, int out_size, void* d_ws, size_t ws_size,
                              hipStream_t stream) {
    const float* x  = (const float*)d_in[0];
    const float* W1 = (const float*)d_in[1];
    const float* W2 = (const float*)d_in[2];
    const float* b2 = (const float*)d_in[3];
    const int*   ei = (const int*)d_in[4];

    int n  = in_sizes[0] / D;   // 100000
    int nE = in_sizes[4] / 2;   // 1600000
    const int* src = ei;        // message source
    const int* dst = ei + nE;   // aggregation target

    int B = (n + BKT_NODES - 1) >> BKT_SHIFT;  // 391 buckets

    // workspace layout (aligned to 256B):
    //   row_ptr | dinv | cursor [MAXB] | adj [nE] | packed [(B+1)*CAP] |
    //   F0 [n*D/2 u32, bf16] | F1 [n*D/2 u32, bf16]
    auto align = [](size_t v) { return (v + 255) & ~(size_t)255; };
    char* ws = (char*)d_ws;
    size_t off = 0;
    int* row_ptr = (int*)(ws + off);   off += align((size_t)(n + 1) * 4);
    float* dinv  = (float*)(ws + off); off += align((size_t)n * 4);
    int* cursor  = (int*)(ws + off);   off += align((size_t)MAXB * 4);
    int* adj     = (int*)(ws + off);   off += align((size_t)nE * 4);
    int* packed  = (int*)(ws + off);   off += align((size_t)(B + 1) * CAP * 4);
    u32* F0      = (u32*)(ws + off);   off += align((size_t)n * (D / 2) * 4);
    u32* F1      = (u32*)(ws + off);
    float* out = (float*)d_out;

    int nchunks = (nE + CHUNK - 1) / CHUNK;  // 391

    // CSR build: memset + 2 dispatches
    hipMemsetAsync(cursor, 0, (size_t)MAXB * 4, stream);
    partition<<<nchunks, 1024, 0, stream>>>(src, dst, cursor, packed, nE, B);
    bucket_csr<<<B, 1024, 0, stream>>>(packed, cursor, row_ptr, dinv, adj, x, F0, n, B);

    int gblocks = (n + GROWS - 1) / GROWS;  // 1563

    // layer 1: F1 = bf16(dinv*relu(dinv*(gather(F0)@W1)))   (separate buffer:
    // gather reads F0 cross-block while we write -> no in-place)
    fused<0><<<gblocks, 256, 0, stream>>>(F0, row_ptr, adj, W1, nullptr, dinv, nullptr, F1, n);

    // layer 2: out = dinv*(gather(F1)@W2) + b2
    fused<1><<<gblocks, 256, 0, stream>>>(F1, row_ptr, adj, W2, b2, dinv, out, nullptr, n);
}